// Round 3
// baseline (95.727 us; speedup 1.0000x reference)
//
#include <hip/hip_runtime.h>

// Reprojection residual for bundle adjustment.
// Inputs (setup_inputs order):
//   d_in[0] observe : float32 [N_OBS, 2]
//   d_in[1] cidx    : int32   [N_OBS]
//   d_in[2] pidx    : int32   [N_OBS]
//   d_in[3] K       : float32 [N_CAMS, 3]   (focal, k1, k2)
//   d_in[4] C       : float32 [N_CAMS, 7]   (t.xyz, q.xyzw)
//   d_in[5] P       : float32 [N_PTS, 3]
// Output: float32 [N_OBS, 2]
//
// R3: same as R2 (4 obs/thread, gathers issued before compute, nontemporal
// streaming) but with clang ext_vector types for the nontemporal builtins
// (HIP_vector_type structs are rejected by __builtin_nontemporal_*).

typedef int   vi4 __attribute__((ext_vector_type(4)));
typedef float vf4 __attribute__((ext_vector_type(4)));

__device__ __forceinline__ void reproj_one(
    float vx, float vy, float vz,
    const float cam[7], const float kk[3],
    float obx, float oby, float* ox, float* oy)
{
    float tx = cam[0], ty = cam[1], tz = cam[2];
    float qx = cam[3], qy = cam[4], qz = cam[5], qw = cam[6];

    // uv = cross(qv, v)
    float uvx = qy * vz - qz * vy;
    float uvy = qz * vx - qx * vz;
    float uvz = qx * vy - qy * vx;
    // uuv = cross(qv, uv)
    float uuvx = qy * uvz - qz * uvy;
    float uuvy = qz * uvx - qx * uvz;
    float uuvz = qx * uvy - qy * uvx;

    float cpx = vx + 2.0f * (qw * uvx + uuvx) + tx;
    float cpy = vy + 2.0f * (qw * uvy + uuvy) + ty;
    float cpz = vz + 2.0f * (qw * uvz + uuvz) + tz;

    float nx = -cpx / cpz;
    float ny = -cpy / cpz;
    float r  = nx * nx + ny * ny;

    float dist = 1.0f + kk[1] * r + kk[2] * r * r;
    float fd   = kk[0] * dist;

    *ox = fd * nx - obx;
    *oy = fd * ny - oby;
}

__global__ __launch_bounds__(256) void reproj_kernel(
    const float*  __restrict__ observe,
    const int*    __restrict__ cidx,
    const int*    __restrict__ pidx,
    const float*  __restrict__ K,
    const float*  __restrict__ C,
    const float*  __restrict__ P,
    float*        __restrict__ out,
    int n)
{
    int base = (blockIdx.x * 256 + threadIdx.x) * 4;
    if (base >= n) return;

    if (base + 4 <= n) {
        // ---- streaming loads (nontemporal, vectorized) ----
        vi4 c4 = __builtin_nontemporal_load((const vi4*)(cidx + base));
        vi4 p4 = __builtin_nontemporal_load((const vi4*)(pidx + base));
        vf4 ob01 = __builtin_nontemporal_load((const vf4*)(observe + 2 * base));
        vf4 ob23 = __builtin_nontemporal_load((const vf4*)(observe + 2 * base + 4));

        int ci[4] = { c4.x, c4.y, c4.z, c4.w };
        int pi[4] = { p4.x, p4.y, p4.z, p4.w };

        // ---- issue ALL gathers before compute (max MLP) ----
        float v[4][3], cam[4][7], kk[4][3];
        #pragma unroll
        for (int k = 0; k < 4; ++k) {
            const float* Pp = P + 3 * pi[k];
            v[k][0] = Pp[0]; v[k][1] = Pp[1]; v[k][2] = Pp[2];
        }
        #pragma unroll
        for (int k = 0; k < 4; ++k) {
            const float* Cc = C + 7 * ci[k];
            #pragma unroll
            for (int j = 0; j < 7; ++j) cam[k][j] = Cc[j];
        }
        #pragma unroll
        for (int k = 0; k < 4; ++k) {
            const float* Kc = K + 3 * ci[k];
            kk[k][0] = Kc[0]; kk[k][1] = Kc[1]; kk[k][2] = Kc[2];
        }

        float res[8];
        reproj_one(v[0][0], v[0][1], v[0][2], cam[0], kk[0], ob01.x, ob01.y, &res[0], &res[1]);
        reproj_one(v[1][0], v[1][1], v[1][2], cam[1], kk[1], ob01.z, ob01.w, &res[2], &res[3]);
        reproj_one(v[2][0], v[2][1], v[2][2], cam[2], kk[2], ob23.x, ob23.y, &res[4], &res[5]);
        reproj_one(v[3][0], v[3][1], v[3][2], cam[3], kk[3], ob23.z, ob23.w, &res[6], &res[7]);

        vf4 o0 = { res[0], res[1], res[2], res[3] };
        vf4 o1 = { res[4], res[5], res[6], res[7] };
        __builtin_nontemporal_store(o0, (vf4*)(out + 2 * base));
        __builtin_nontemporal_store(o1, (vf4*)(out + 2 * base + 4));
    } else {
        // tail (n not divisible by 4)
        for (int i = base; i < n; ++i) {
            int c = cidx[i];
            int p = pidx[i];
            const float* Pp = P + 3 * p;
            const float* Cc = C + 7 * c;
            const float* Kc = K + 3 * c;
            float cam[7], kk[3];
            #pragma unroll
            for (int j = 0; j < 7; ++j) cam[j] = Cc[j];
            kk[0] = Kc[0]; kk[1] = Kc[1]; kk[2] = Kc[2];
            float ox, oy;
            reproj_one(Pp[0], Pp[1], Pp[2], cam, kk,
                       observe[2 * i], observe[2 * i + 1], &ox, &oy);
            out[2 * i]     = ox;
            out[2 * i + 1] = oy;
        }
    }
}

extern "C" void kernel_launch(void* const* d_in, const int* in_sizes, int n_in,
                              void* d_out, int out_size, void* d_ws, size_t ws_size,
                              hipStream_t stream)
{
    const float* observe = (const float*)d_in[0];
    const int*   cidx    = (const int*)d_in[1];
    const int*   pidx    = (const int*)d_in[2];
    const float* K       = (const float*)d_in[3];
    const float* C       = (const float*)d_in[4];
    const float* P       = (const float*)d_in[5];
    float*       out     = (float*)d_out;

    int n = in_sizes[1];                       // N_OBS
    int threads = (n + 3) / 4;                 // 4 obs per thread
    int block = 256;
    int grid  = (threads + block - 1) / block;

    reproj_kernel<<<grid, block, 0, stream>>>(observe, cidx, pidx, K, C, P, out, n);
}

// Round 4
// 70.011 us; speedup vs baseline: 1.3673x; 1.3673x over previous
//
#include <hip/hip_runtime.h>

// Reprojection residual for bundle adjustment.
// Inputs (setup_inputs order):
//   d_in[0] observe : float32 [N_OBS, 2]
//   d_in[1] cidx    : int32   [N_OBS]
//   d_in[2] pidx    : int32   [N_OBS]
//   d_in[3] K       : float32 [N_CAMS, 3]   (focal, k1, k2)
//   d_in[4] C       : float32 [N_CAMS, 7]   (t.xyz, q.xyzw)
//   d_in[5] P       : float32 [N_PTS, 3]
// Output: float32 [N_OBS, 2]
//
// R4: all camera data (K+C, 2000 cams) cached in LDS as 12-float records
// (96 KB dynamic LDS, 1024-thread blocks). Per-obs camera access becomes
// 3x ds_read_b128; only the P gather stays on the global/L1 path. This
// attacks the TA/L1 divergent-gather serialization that R3 showed
// (95 us at 27% HBM, VALUBusy 9% -> request-pipe bound, not BW bound).

typedef int   vi4 __attribute__((ext_vector_type(4)));
typedef float vf4 __attribute__((ext_vector_type(4)));

__device__ __forceinline__ void reproj_one(
    float vx, float vy, float vz,
    vf4 r0, vf4 r1, vf4 r2,
    float obx, float oby, float* ox, float* oy)
{
    // record layout: [f, k1, k2, tx, ty, tz, qx, qy, qz, qw, 0, 0]
    float f  = r0.x, k1 = r0.y, k2 = r0.z;
    float tx = r0.w, ty = r1.x, tz = r1.y;
    float qx = r1.z, qy = r1.w, qz = r2.x, qw = r2.y;

    // uv = cross(qv, v)
    float uvx = qy * vz - qz * vy;
    float uvy = qz * vx - qx * vz;
    float uvz = qx * vy - qy * vx;
    // uuv = cross(qv, uv)
    float uuvx = qy * uvz - qz * uvy;
    float uuvy = qz * uvx - qx * uvz;
    float uuvz = qx * uvy - qy * uvx;

    float cpx = vx + 2.0f * (qw * uvx + uuvx) + tx;
    float cpy = vy + 2.0f * (qw * uvy + uuvy) + ty;
    float cpz = vz + 2.0f * (qw * uvz + uuvz) + tz;

    float nx = -cpx / cpz;
    float ny = -cpy / cpz;
    float r  = nx * nx + ny * ny;

    float dist = 1.0f + k1 * r + k2 * r * r;
    float fd   = f * dist;

    *ox = fd * nx - obx;
    *oy = fd * ny - oby;
}

__global__ __launch_bounds__(1024) void reproj_kernel(
    const float*  __restrict__ observe,
    const int*    __restrict__ cidx,
    const int*    __restrict__ pidx,
    const float*  __restrict__ K,
    const float*  __restrict__ C,
    const float*  __restrict__ P,
    float*        __restrict__ out,
    int n, int ncams)
{
    extern __shared__ float cam_lds[];   // 12 floats per camera

    // ---- cooperative LDS fill: all cameras resident ----
    for (int c = threadIdx.x; c < ncams; c += 1024) {
        const float* Kc = K + 3 * c;
        const float* Cc = C + 7 * c;
        float* r = cam_lds + 12 * c;
        r[0] = Kc[0]; r[1] = Kc[1]; r[2] = Kc[2];
        r[3] = Cc[0]; r[4] = Cc[1]; r[5] = Cc[2];
        r[6] = Cc[3]; r[7] = Cc[4]; r[8] = Cc[5]; r[9] = Cc[6];
    }
    __syncthreads();

    int base = (blockIdx.x * 1024 + threadIdx.x) * 4;
    if (base >= n) return;

    if (base + 4 <= n) {
        // streaming loads (nontemporal, vectorized)
        vi4 c4 = __builtin_nontemporal_load((const vi4*)(cidx + base));
        vi4 p4 = __builtin_nontemporal_load((const vi4*)(pidx + base));
        vf4 ob01 = __builtin_nontemporal_load((const vf4*)(observe + 2 * base));
        vf4 ob23 = __builtin_nontemporal_load((const vf4*)(observe + 2 * base + 4));

        int ci[4] = { c4.x, c4.y, c4.z, c4.w };
        int pi[4] = { p4.x, p4.y, p4.z, p4.w };

        // issue all P gathers first (the only remaining global gather)
        float v[4][3];
        #pragma unroll
        for (int k = 0; k < 4; ++k) {
            const float* Pp = P + 3 * pi[k];
            v[k][0] = Pp[0]; v[k][1] = Pp[1]; v[k][2] = Pp[2];
        }

        float res[8];
        #pragma unroll
        for (int k = 0; k < 4; ++k) {
            const vf4* camv = (const vf4*)(cam_lds + 12 * ci[k]);
            vf4 r0 = camv[0], r1 = camv[1], r2 = camv[2];
            float obx = (k == 0) ? ob01.x : (k == 1) ? ob01.z : (k == 2) ? ob23.x : ob23.z;
            float oby = (k == 0) ? ob01.y : (k == 1) ? ob01.w : (k == 2) ? ob23.y : ob23.w;
            reproj_one(v[k][0], v[k][1], v[k][2], r0, r1, r2,
                       obx, oby, &res[2 * k], &res[2 * k + 1]);
        }

        vf4 o0 = { res[0], res[1], res[2], res[3] };
        vf4 o1 = { res[4], res[5], res[6], res[7] };
        __builtin_nontemporal_store(o0, (vf4*)(out + 2 * base));
        __builtin_nontemporal_store(o1, (vf4*)(out + 2 * base + 4));
    } else {
        // tail (unused when n % 4 == 0, kept for safety)
        for (int i = base; i < n; ++i) {
            int c = cidx[i];
            int p = pidx[i];
            const vf4* camv = (const vf4*)(cam_lds + 12 * c);
            vf4 r0 = camv[0], r1 = camv[1], r2 = camv[2];
            const float* Pp = P + 3 * p;
            float ox, oy;
            reproj_one(Pp[0], Pp[1], Pp[2], r0, r1, r2,
                       observe[2 * i], observe[2 * i + 1], &ox, &oy);
            out[2 * i]     = ox;
            out[2 * i + 1] = oy;
        }
    }
}

extern "C" void kernel_launch(void* const* d_in, const int* in_sizes, int n_in,
                              void* d_out, int out_size, void* d_ws, size_t ws_size,
                              hipStream_t stream)
{
    const float* observe = (const float*)d_in[0];
    const int*   cidx    = (const int*)d_in[1];
    const int*   pidx    = (const int*)d_in[2];
    const float* K       = (const float*)d_in[3];
    const float* C       = (const float*)d_in[4];
    const float* P       = (const float*)d_in[5];
    float*       out     = (float*)d_out;

    int n     = in_sizes[1];          // N_OBS
    int ncams = in_sizes[3] / 3;      // K is [N_CAMS, 3]

    int block = 1024;
    int obs_per_block = block * 4;
    int grid = (n + obs_per_block - 1) / obs_per_block;
    size_t lds_bytes = (size_t)ncams * 12 * sizeof(float);   // 96 KB for 2000 cams

    reproj_kernel<<<grid, block, lds_bytes, stream>>>(
        observe, cidx, pidx, K, C, P, out, n, ncams);
}